// Round 25
// baseline (265.169 us; speedup 1.0000x reference)
//
#include <hip/hip_runtime.h>
#include <math.h>

// ---------------------------------------------------------------------------
// ResCNN_ASP_SpeakerEncoder — v25 = TT=80 tile (between v23's 128 and v24's
// 64): LDS 49152 B => 3 blocks/CU like TT=64, but halo fraction 1.20 and
// NCH=38 keep the per-block amortization close to TT=128. Same quantization
// points / clamp idiom => absmax exactly 0.015625. Fallback: v23 (240.4us).
// ---------------------------------------------------------------------------

constexpr int B_  = 64;
constexpr int T_  = 3000;
constexpr int NB_ = 257;   // NBINS
constexpr int R_  = B_ * T_;           // 192000 rows
constexpr int NCH = 38;                // chunks (38 x 80 >= 3000)

// workspace layout (float offsets)
constexpr size_t OFF_BS    = 0;
constexpr size_t OFF_WEFF  = 128;                          // ushort hi[64*320]+lo
constexpr size_t OFF_WTAIL = OFF_WEFF + 20480;
constexpr size_t OFF_W1    = OFF_WTAIL + 128;              // ushort hi+lo 3*128*64
constexpr size_t OFF_W2    = OFF_W1  + 3*64*128;
constexpr size_t OFF_W3    = OFF_W2  + 3*128*128;
constexpr size_t OFF_WA1   = OFF_W3  + 3*128*128;
constexpr size_t OFF_WA2   = OFF_WA1 + 8192;
constexpr size_t SZ_P      = (size_t)B_*NCH*128;
constexpr size_t OFF_PM    = OFF_WA2 + 8192;
constexpr size_t OFF_PS    = OFF_PM  + SZ_P;
constexpr size_t OFF_PCM   = OFF_PS  + SZ_P;
constexpr size_t OFF_PCQ   = OFF_PCM + SZ_P;
// single bf16 planes
constexpr size_t OFF_HS    = OFF_PCQ + SZ_P;               // h  [R*64]u
constexpr size_t OFF_AS    = OFF_HS  + (size_t)R_*32;      // slack (DMA overrun)
constexpr size_t OFF_WL2T  = OFF_AS  + (size_t)R_*32 + 4096; // fp32 [256][512]

typedef __attribute__((ext_vector_type(8))) short  bf16x8;
typedef __attribute__((ext_vector_type(4))) float  f32x4;
typedef __attribute__((ext_vector_type(4), aligned(4))) float float4a;
typedef unsigned short ushort_t;

typedef __attribute__((address_space(3))) unsigned int        as3_u32;
typedef const __attribute__((address_space(1))) unsigned int  as1_u32c;
__device__ __forceinline__ void gload16(const void* g, void* l) {
    __builtin_amdgcn_global_load_lds((as1_u32c*)g, (as3_u32*)l, 16, 0, 0);
}

__device__ inline ushort_t f2bf(float f) {                // RNE f32->bf16
    unsigned u = __float_as_uint(f);
    unsigned r = u + 0x7FFFu + ((u >> 16) & 1u);
    return (ushort_t)(r >> 16);
}
__device__ inline float bf2f(ushort_t h) {
    return __uint_as_float(((unsigned)h) << 16);
}
__device__ inline void split2(float v, ushort_t &h, ushort_t &l) {
    h = f2bf(v);
    l = f2bf(v - bf2f(h));
}

// fast tanh: (e^{2x}-1)/(e^{2x}+1), clamp +-15
__device__ inline float fast_tanh(float x) {
    float cx = fminf(fmaxf(x, -15.0f), 15.0f);
    float e  = __expf(2.0f * cx);
    return __fdividef(e - 1.0f, e + 1.0f);
}

// pack 4 f32 -> 4 bf16 (RNE, 2 u32)
__device__ inline void pack_hi4(float x, float y, float z, float w, uint2 &ph) {
    unsigned hx, hy;
    asm("v_cvt_pk_bf16_f32 %0, %1, %2" : "=v"(hx) : "v"(x), "v"(y));
    asm("v_cvt_pk_bf16_f32 %0, %1, %2" : "=v"(hy) : "v"(z), "v"(w));
    ph.x = hx; ph.y = hy;
}

// ---------------------------------------------------------------------------
__global__ void sort_kernel(const float* __restrict__ bp, float* __restrict__ bs) {
    if (threadIdx.x == 0) {
        float tmp[82];
        for (int i = 0; i < 82; ++i) tmp[i] = bp[i];
        for (int i = 1; i < 82; ++i) {
            float key = tmp[i];
            int j = i - 1;
            while (j >= 0 && tmp[j] > key) { tmp[j+1] = tmp[j]; --j; }
            tmp[j+1] = key;
        }
        for (int i = 0; i < 82; ++i) bs[i] = tmp[i];
    }
}

// Fragment-order packing (B: lane&15=col, lane>>4=k-octet; A: lane&15=row),
// plus fp32 wl2 transpose [256 j][512 o]. (lo planes still written; unused.)
__global__ void prep_kernel(const float* __restrict__ bs, const float* __restrict__ wl1,
                            const float* __restrict__ wc1, const float* __restrict__ wc2,
                            const float* __restrict__ wc3, const float* __restrict__ wa1,
                            const float* __restrict__ wa2, const float* __restrict__ wl2,
                            ushort_t* __restrict__ weh, ushort_t* __restrict__ wel,
                            float* __restrict__ wtail,
                            ushort_t* __restrict__ w1h, ushort_t* __restrict__ w1l,
                            ushort_t* __restrict__ w2h, ushort_t* __restrict__ w2l,
                            ushort_t* __restrict__ w3h, ushort_t* __restrict__ w3l,
                            ushort_t* __restrict__ wa1h, ushort_t* __restrict__ wa1l,
                            ushort_t* __restrict__ wa2h, ushort_t* __restrict__ wa2l,
                            float* __restrict__ wl2t) {
    int gid = blockIdx.x * 256 + threadIdx.x;
    if (gid < 64*320) {                            // Weff[o][f]
        int o = gid / 320, f = gid % 320;
        if (f > 256) return;
        float acc = 0.0f;
        if (f == 0) acc = wl1[o*80];               // filt[:,:,0] = x[:,:,0]
        else {
            for (int n = 1; n < 79; ++n) {
                float bn = bs[n], bn1 = bs[n+1], bn2 = bs[n+2];
                int ibn  = (int)floorf(bn);
                int ibn1 = (int)floorf(bn1);
                int ibn2 = (int)floorf(bn2);
                float fbv = 0.0f;
                if (f >= ibn && f < ibn1) {
                    float d = (bn1-bn)*(bn1-bn);
                    fbv = ((float)f - bn) / (d > 0.0f ? d : 1.0f);
                } else if (f >= ibn1 && f < ibn2) {
                    float d = (bn2-bn1)*(bn2-bn1);
                    fbv = (bn2 - (float)f) / (d > 0.0f ? d : 1.0f);
                }
                acc += wl1[o*80 + n] * fbv;
            }
        }
        if (f == 256) { wtail[o] = acc; return; }
        int kc = f >> 5, lane = ((f & 31) >> 3)*16 + (o & 15), e = f & 7;
        size_t dst = (((size_t)kc*4 + (o >> 4))*64 + lane)*8 + e;
        split2(acc, weh[dst], wel[dst]);
        return;
    }
    gid -= 64*320;
    if (gid < 3*128*64) {                          // conv1: [k][c][ci=64]
        int k = gid / (128*64), rem = gid % (128*64);
        int c = rem >> 6, ci = rem & 63;
        float v = wc1[(c*64 + ci)*3 + k];
        int lane = ((ci & 31) >> 3)*16 + (c & 15), e = ci & 7;
        size_t dst = ((((size_t)k*2 + (ci >> 5))*8 + (c >> 4))*64 + lane)*8 + e;
        split2(v, w1h[dst], w1l[dst]);
        return;
    }
    gid -= 3*128*64;
    if (gid < 3*128*128) {                         // conv2
        int k = gid / (128*128), rem = gid % (128*128);
        int c = rem >> 7, ci = rem & 127;
        float v = wc2[(c*128 + ci)*3 + k];
        int lane = ((ci & 31) >> 3)*16 + (c & 15), e = ci & 7;
        size_t dst = ((((size_t)k*4 + (ci >> 5))*8 + (c >> 4))*64 + lane)*8 + e;
        split2(v, w2h[dst], w2l[dst]);
        return;
    }
    gid -= 3*128*128;
    if (gid < 3*128*128) {                         // conv3
        int k = gid / (128*128), rem = gid % (128*128);
        int c = rem >> 7, ci = rem & 127;
        float v = wc3[(c*128 + ci)*3 + k];
        int lane = ((ci & 31) >> 3)*16 + (c & 15), e = ci & 7;
        size_t dst = ((((size_t)k*4 + (ci >> 5))*8 + (c >> 4))*64 + lane)*8 + e;
        split2(v, w3h[dst], w3l[dst]);
        return;
    }
    gid -= 3*128*128;
    if (gid < 64*128) {                            // wa1 [c=64][ci=128]
        int c = gid >> 7, ci = gid & 127;
        float v = wa1[gid];
        int lane = ((ci & 31) >> 3)*16 + (c & 15), e = ci & 7;
        size_t dst = (((size_t)(ci >> 5)*4 + (c >> 4))*64 + lane)*8 + e;
        split2(v, wa1h[dst], wa1l[dst]);
        return;
    }
    gid -= 64*128;
    if (gid < 128*64) {                            // wa2 [n=128][ci=64] (A op)
        int n = gid >> 6, ci = gid & 63;
        float v = wa2[gid];
        int lane = ((ci & 31) >> 3)*16 + (n & 15), e = ci & 7;
        size_t dst = (((size_t)(ci >> 5)*8 + (n >> 4))*64 + lane)*8 + e;
        split2(v, wa2h[dst], wa2l[dst]);
        return;
    }
    gid -= 128*64;
    if (gid < 256*512) {                           // wl2T[j][o] <- wl2[o][j]
        int j = gid >> 9, o = gid & 511;
        wl2t[gid] = wl2[(size_t)o*256 + j];
        return;
    }
}

// ---------------------------------------------------------------------------
// lin1: h = relu(x @ Weff^T + b); x staged as single bf16; 1-pass MFMA.
__launch_bounds__(256)
__global__ void lin1_mfma(const float* __restrict__ X,
                          const ushort_t* __restrict__ Wh,
                          const float* __restrict__ wtail,
                          const float* __restrict__ bias,
                          ushort_t* __restrict__ Hs) {
    __shared__ __align__(16) ushort_t ash[128*64];
    __shared__ float xs[128];
    __shared__ float wts[64];
    const int tid  = threadIdx.x;
    const int lane = tid & 63;
    const int wid  = tid >> 6;
    const int wy   = wid >> 1, wx = wid & 1;
    const int l16  = lane & 15, l4 = lane >> 4;
    const int r0   = blockIdx.x * 128;

    if (tid < 128)       xs[tid] = X[(size_t)(r0 + tid)*NB_ + 256];
    else if (tid < 192)  wts[tid - 128] = wtail[tid - 128];

#define LIN1_LOAD(dst, k0)                                            \
    _Pragma("unroll")                                                 \
    for (int i = 0; i < 8; ++i) {                                     \
        int q = tid + i*256; int r = q >> 4, cc = (q & 15) << 2;      \
        dst[i] = *(const float4a*)(X + (size_t)(r0 + r)*NB_ + (k0) + cc); \
    }
#define LIN1_CW(src)                                                  \
    _Pragma("unroll")                                                 \
    for (int i = 0; i < 8; ++i) {                                     \
        int q = tid + i*256; int r = q >> 4, cc = (q & 15) << 2;      \
        uint2 ph;                                                     \
        pack_hi4(src[i].x, src[i].y, src[i].z, src[i].w, ph);         \
        unsigned byte = ((unsigned)(r*64 + cc))*2u ^ ((unsigned)((r & 7) << 4)); \
        *(uint2*)((char*)ash + byte) = ph;                            \
    }

    float4a bufA[8], bufB[8];
    LIN1_LOAD(bufA, 0);

    f32x4 acc[4][2];
    const f32x4 z = {0.f,0.f,0.f,0.f};
#pragma unroll
    for (int m = 0; m < 4; ++m) { acc[m][0] = z; acc[m][1] = z; }

#pragma unroll
    for (int ck = 0; ck < 4; ++ck) {
        const float4a* cur = (ck & 1) ? bufB : bufA;
        float4a*       nxt = (ck & 1) ? bufA : bufB;
        if (ck < 3) LIN1_LOAD(nxt, (ck + 1)*64);
        LIN1_CW(cur);
        __syncthreads();
#pragma unroll
        for (int kk = 0; kk < 64; kk += 32) {
            bf16x8 bh[2];
#pragma unroll
            for (int n = 0; n < 2; ++n) {
                size_t off = (((size_t)(ck*2 + (kk >> 5))*4 + wx*2 + n)*64 + lane)*8;
                bh[n] = *(const bf16x8*)(Wh + off);
            }
            bf16x8 fh[4];
#pragma unroll
            for (int m = 0; m < 4; ++m) {
                int r = wy*64 + m*16 + l16;
                unsigned byte = ((unsigned)(r*64 + kk + l4*8))*2u ^ ((unsigned)((r & 7) << 4));
                fh[m] = *(const bf16x8*)((const char*)ash + byte);
            }
#pragma unroll
            for (int m = 0; m < 4; ++m)
#pragma unroll
                for (int n = 0; n < 2; ++n)
                    acc[m][n] = __builtin_amdgcn_mfma_f32_16x16x32_bf16(fh[m], bh[n], acc[m][n], 0, 0, 0);
        }
        __syncthreads();
    }
#undef LIN1_LOAD
#undef LIN1_CW

#pragma unroll
    for (int m = 0; m < 4; ++m)
#pragma unroll
        for (int n = 0; n < 2; ++n) {
            int c = wx*32 + n*16 + l16;
            float bv = bias[c];
            float wc = wts[c];
            int rbl = wy*64 + m*16 + l4*4;
#pragma unroll
            for (int rg = 0; rg < 4; ++rg) {
                int rl = rbl + rg;
                float v = fmaxf(acc[m][n][rg] + bv + xs[rl]*wc, 0.0f);
                Hs[(size_t)(r0 + rl)*64 + c] = f2bf(v);
            }
        }
}

// ---------------------------------------------------------------------------
// Fused conv1+conv2+conv3+ASP, TT=80 per (chunk, b). LDS 49152B = 3 blk/CU.
// hs [100][64] (rows t0-10..t0+89) aliased under ss_; i1s [96][128];
// ss_ [96][128] holds s then i3 in-place (register staging); vs_ [80][64]
// aliases dead i1s.
__launch_bounds__(512, 6)
__global__ void dconv123_asp(const ushort_t* __restrict__ Hs,
                             const ushort_t* __restrict__ W1h,
                             const ushort_t* __restrict__ W2h,
                             const ushort_t* __restrict__ W3h,
                             const float* __restrict__ bc1, const float* __restrict__ bc2,
                             const float* __restrict__ bc3,
                             const ushort_t* __restrict__ Wa1h,
                             const ushort_t* __restrict__ Wa2h,
                             const float* __restrict__ ba1, const float* __restrict__ ba2,
                             float* __restrict__ pm, float* __restrict__ ps,
                             float* __restrict__ pcm, float* __restrict__ pcq) {
    __shared__ __align__(16) char smem[49152];
    ushort_t* hs_ = (ushort_t*)smem;               // [100][64] rows t0-10..t0+89
    ushort_t* ss_ = (ushort_t*)smem;               // s/i3 [96][128] (hs dead first)
    ushort_t* i1s = (ushort_t*)(smem + 24576);     // i1 [96][128]
    ushort_t* vs_ = (ushort_t*)(smem + 24576);     // v [80][64] (i1 dead)

    const int tid  = threadIdx.x;
    const int lane = tid & 63;
    const int wid  = tid >> 6;            // 0..7
    const int l16  = lane & 15, l4 = lane >> 4;
    const int ch   = blockIdx.x;
    const int b    = blockIdx.y;
    const int t0   = ch * 80;

    // ---- stage h rows [t0-10, t0+90): 100 rows x 64ch = 800 chunks of 16B ----
    const long long rowbase_h = ((long long)b*T_ + (t0 - 10)) * 64;
    for (int c0 = wid*64; c0 < 800; c0 += 512) {   // 800 real, overrun to 831 ok
        int ck = c0 + lane;
        int r  = ck >> 3;
        int sc = ck ^ (r & 7);
        gload16(Hs + rowbase_h + (long long)sc*8, (char*)hs_ + (size_t)c0*16);
    }
    __syncthreads();
    if (t0 < 10 || t0 + 90 > T_) {                 // zero OOB-global h rows
        for (int idx = tid; idx < 100*64/4; idx += 512) {
            int e = idx << 2;
            int r = e >> 6, ci = e & 63;
            int t = t0 - 10 + r;
            if (t < 0 || t >= T_) {
                unsigned byte = ((unsigned)(r*64 + ci))*2u ^ ((unsigned)((r & 7) << 4));
                *(uint2*)((char*)hs_ + byte) = make_uint2(0u, 0u);
            }
        }
        __syncthreads();
    }

    // ---- phase 0: conv1 over 96 i1 rows (reads hs) -> i1s (OOB t -> 0) ----
    {
        f32x4 acc[6];
        const f32x4 z = {0.f,0.f,0.f,0.f};
#pragma unroll
        for (int m = 0; m < 6; ++m) acc[m] = z;
#pragma unroll
        for (int k = 0; k < 3; ++k) {
#pragma unroll
            for (int cb = 0; cb < 2; ++cb) {
                size_t off = ((((size_t)k*2 + cb)*8 + wid)*64 + lane)*8;
                bf16x8 bh = *(const bf16x8*)(W1h + off);
#pragma unroll
                for (int m = 0; m < 6; ++m) {
                    int r = m*16 + l16 + 2*k;          // hs row, in [0,99]
                    unsigned byte = ((unsigned)(r*64 + cb*32 + l4*8))*2u
                                  ^ ((unsigned)((r & 7) << 4));
                    bf16x8 ah = *(const bf16x8*)((const char*)hs_ + byte);
                    acc[m] = __builtin_amdgcn_mfma_f32_16x16x32_bf16(ah, bh, acc[m], 0, 0, 0);
                }
            }
        }
        const int c = wid*16 + l16;
        const float bv = bc1[c];
#pragma unroll
        for (int m = 0; m < 6; ++m) {
#pragma unroll
            for (int rg = 0; rg < 4; ++rg) {
                int rl = m*16 + l4*4 + rg;             // i1 local row 0..95
                int t  = t0 - 8 + rl;
                float v = (t >= 0 && t < T_) ? (acc[m][rg] + bv) : 0.0f;
                unsigned byte = ((unsigned)(rl*128 + c))*2u ^ ((unsigned)((rl & 15) << 4));
                *(ushort_t*)((char*)i1s + byte) = f2bf(v);
            }
        }
    }
    __syncthreads();                       // hs reads done; i1s ready

    // ---- phase 1: conv2 over all 96 local rows -> s = conv2 + bc2 + 2*i1 ----
    {
        f32x4 acc[6];
        const f32x4 z = {0.f,0.f,0.f,0.f};
#pragma unroll
        for (int m = 0; m < 6; ++m) acc[m] = z;
#pragma unroll
        for (int k = 0; k < 3; ++k) {
#pragma unroll
            for (int cb = 0; cb < 4; ++cb) {
                size_t off = ((((size_t)k*4 + cb)*8 + wid)*64 + lane)*8;
                bf16x8 bh = *(const bf16x8*)(W2h + off);
#pragma unroll
                for (int m = 0; m < 6; ++m) {
                    int r = m*16 + l16 + k*3 - 3;
                    r = min(max(r, 0), 95);   // garbage edge rows; never consumed
                    unsigned byte = ((unsigned)(r*128 + cb*32 + l4*8))*2u
                                  ^ ((unsigned)((r & 15) << 4));
                    bf16x8 ah = *(const bf16x8*)((const char*)i1s + byte);
                    acc[m] = __builtin_amdgcn_mfma_f32_16x16x32_bf16(ah, bh, acc[m], 0, 0, 0);
                }
            }
        }
        const int c = wid*16 + l16;
        const float bv = bc2[c];
#pragma unroll
        for (int m = 0; m < 6; ++m) {
#pragma unroll
            for (int rg = 0; rg < 4; ++rg) {
                int rl = m*16 + l4*4 + rg;
                int t  = t0 - 8 + rl;
                float v = 0.0f;
                unsigned byte = ((unsigned)(rl*128 + c))*2u ^ ((unsigned)((rl & 15) << 4));
                if (t >= 0 && t < T_) {
                    float cen = bf2f(*(const ushort_t*)((const char*)i1s + byte));
                    v = acc[m][rg] + bv + 2.0f*cen;
                }
                *(ushort_t*)((char*)ss_ + byte) = f2bf(v);
            }
        }
    }
    __syncthreads();

    // ---- phase 2: conv3 + residual into REGISTERS (reads s) ----
    float i3r[5][4];
    {
        f32x4 acc[5];
        const f32x4 z = {0.f,0.f,0.f,0.f};
#pragma unroll
        for (int m = 0; m < 5; ++m) acc[m] = z;
#pragma unroll
        for (int k = 0; k < 3; ++k) {
#pragma unroll
            for (int cb = 0; cb < 4; ++cb) {
                size_t off = ((((size_t)k*4 + cb)*8 + wid)*64 + lane)*8;
                bf16x8 bh = *(const bf16x8*)(W3h + off);
#pragma unroll
                for (int m = 0; m < 5; ++m) {
                    int r = 8 + m*16 + l16 + k*4 - 4;  // in [4,91]
                    unsigned byte = ((unsigned)(r*128 + cb*32 + l4*8))*2u
                                  ^ ((unsigned)((r & 15) << 4));
                    bf16x8 ah = *(const bf16x8*)((const char*)ss_ + byte);
                    acc[m] = __builtin_amdgcn_mfma_f32_16x16x32_bf16(ah, bh, acc[m], 0, 0, 0);
                }
            }
        }
        const int c = wid*16 + l16;
        const float bv = bc3[c];
#pragma unroll
        for (int m = 0; m < 5; ++m)
#pragma unroll
            for (int rg = 0; rg < 4; ++rg) {
                int rl = 8 + m*16 + l4*4 + rg;         // in [8,88)
                unsigned byte = ((unsigned)(rl*128 + c))*2u ^ ((unsigned)((rl & 15) << 4));
                float cen = bf2f(*(const ushort_t*)((const char*)ss_ + byte));
                i3r[m][rg] = acc[m][rg] + bv + cen;
            }
    }
    __syncthreads();                       // all s reads complete
    // write i3 over s (rows [8,88) = t [t0, t0+80))
    {
        const int c = wid*16 + l16;
#pragma unroll
        for (int m = 0; m < 5; ++m)
#pragma unroll
            for (int rg = 0; rg < 4; ++rg) {
                int rl = 8 + m*16 + l4*4 + rg;
                unsigned byte = ((unsigned)(rl*128 + c))*2u ^ ((unsigned)((rl & 15) << 4));
                *(ushort_t*)((char*)ss_ + byte) = f2bf(i3r[m][rg]);
            }
    }
    __syncthreads();                       // i3 tile ready (i1 dead)

    // ---- ASP stage 1: v = tanh(i3 @ wa1^T + ba1) ----
    // 8 waves = (wy 0..1) x (wx 0..3); wy=0 covers rows 0..47 (m<3),
    // wy=1 covers rows 48..79 (m<2). Wave-uniform predicate.
    {
        const int wy = wid >> 2;
        const int wx = wid & 3;
        const int mmax = (wy == 0) ? 3 : 2;
        f32x4 acc1[3];
        const f32x4 z = {0.f,0.f,0.f,0.f};
#pragma unroll
        for (int m = 0; m < 3; ++m) acc1[m] = z;
#pragma unroll
        for (int kc = 0; kc < 4; ++kc) {
            size_t off = (((size_t)kc*4 + wx)*64 + lane)*8;
            bf16x8 bh = *(const bf16x8*)(Wa1h + off);
#pragma unroll
            for (int m = 0; m < 3; ++m) {
                if (m < mmax) {
                    int rl = 8 + wy*48 + m*16 + l16;   // i3 row in [8,88)
                    unsigned byte = ((unsigned)(rl*128 + kc*32 + l4*8))*2u
                                  ^ ((unsigned)((rl & 15) << 4));
                    bf16x8 ah = *(const bf16x8*)((const char*)ss_ + byte);
                    acc1[m] = __builtin_amdgcn_mfma_f32_16x16x32_bf16(ah, bh, acc1[m], 0, 0, 0);
                }
            }
        }
        const int c = wx*16 + l16;
        const float bv = ba1[c];
#pragma unroll
        for (int m = 0; m < 3; ++m)
            if (m < mmax)
#pragma unroll
                for (int rg = 0; rg < 4; ++rg) {
                    float v = fast_tanh(acc1[m][rg] + bv);
                    int r = wy*48 + m*16 + l4*4 + rg;  // t row in [0,80)
                    unsigned byte = ((unsigned)(r*64 + c))*2u ^ ((unsigned)((r & 7) << 4));
                    *(ushort_t*)((char*)vs_ + byte) = f2bf(v);
                }
    }
    __syncthreads();

    // ---- ASP stage 2 + softmax partials + weighted stats ----
    {
        f32x4 acc2[5];
        const f32x4 z = {0.f,0.f,0.f,0.f};
#pragma unroll
        for (int j = 0; j < 5; ++j) acc2[j] = z;
#pragma unroll
        for (int kc = 0; kc < 2; ++kc) {
            size_t off = (((size_t)kc*8 + wid)*64 + lane)*8;
            bf16x8 awh = *(const bf16x8*)(Wa2h + off);
#pragma unroll
            for (int j = 0; j < 5; ++j) {
                int t = j*16 + l16;
                unsigned byte = ((unsigned)(t*64 + kc*32 + l4*8))*2u
                              ^ ((unsigned)((t & 7) << 4));
                bf16x8 bv_ = *(const bf16x8*)((const char*)vs_ + byte);
                acc2[j] = __builtin_amdgcn_mfma_f32_16x16x32_bf16(awh, bv_, acc2[j], 0, 0, 0);
            }
        }
        const float4 bvv = *(const float4*)&ba2[wid*16 + l4*4];
        const float bva[4] = {bvv.x, bvv.y, bvv.z, bvv.w};
#pragma unroll
        for (int rg = 0; rg < 4; ++rg) {
            const int n = wid*16 + l4*4 + rg;
            float mx = -INFINITY;
#pragma unroll
            for (int j = 0; j < 5; ++j) {
                int tg = t0 + j*16 + l16;
                if (tg < T_) mx = fmaxf(mx, acc2[j][rg] + bva[rg]);
            }
            mx = fmaxf(mx, __shfl_xor(mx, 1));
            mx = fmaxf(mx, __shfl_xor(mx, 2));
            mx = fmaxf(mx, __shfl_xor(mx, 4));
            mx = fmaxf(mx, __shfl_xor(mx, 8));
            float se = 0.0f, am = 0.0f, aq = 0.0f;
#pragma unroll
            for (int j = 0; j < 5; ++j) {
                int tl = j*16 + l16;
                int tg = t0 + tl;
                if (tg < T_) {
                    float p = __expf(acc2[j][rg] + bva[rg] - mx);
                    int rl = tl + 8;
                    unsigned byte = ((unsigned)(rl*128 + n))*2u ^ ((unsigned)((rl & 15) << 4));
                    float x = bf2f(*(const ushort_t*)((const char*)ss_ + byte));
                    se += p; am += p*x; aq += p*x*x;
                }
            }
#pragma unroll
            for (int d = 1; d <= 8; d <<= 1) {
                se += __shfl_xor(se, d);
                am += __shfl_xor(am, d);
                aq += __shfl_xor(aq, d);
            }
            if (l16 == 0) {
                size_t o = ((size_t)b*NCH + ch)*128 + n;
                pm[o]  = mx;
                ps[o]  = se;
                pcm[o] = am;
                pcq[o] = aq;
            }
        }
    }
}

// ---------------------------------------------------------------------------
// final: global softmax combine + stats + layernorm(256) + coalesced linear.
__launch_bounds__(256)
__global__ void final_kernel(const float* __restrict__ pcm, const float* __restrict__ pcq,
                             const float* __restrict__ pm, const float* __restrict__ ps,
                             const float* __restrict__ gamma, const float* __restrict__ beta,
                             const float* __restrict__ w2t, const float* __restrict__ b2,
                             float* __restrict__ out) {
    __shared__ float row[256];
    __shared__ float nrm[256];
    __shared__ float red[8];
    const int tid = threadIdx.x, b = blockIdx.x;
    if (tid < 128) {
        float M = -INFINITY;
        for (int ch = 0; ch < NCH; ++ch)
            M = fmaxf(M, pm[((size_t)b*NCH + ch)*128 + tid]);
        float S = 0.0f, sm = 0.0f, sq = 0.0f;
        for (int ch = 0; ch < NCH; ++ch) {
            size_t o = ((size_t)b*NCH + ch)*128 + tid;
            float m = pm[o];
            if (m > -INFINITY) {
                float e = expf(m - M);
                S  += ps[o]*e;
                sm += pcm[o]*e;
                sq += pcq[o]*e;
            }
        }
        float mean = sm / S;
        float q    = sq / S;
        float resid = q - mean*mean;
        float stdv  = sqrtf(fmaxf(resid, 1e-9f));
        row[tid]       = mean;
        row[128 + tid] = stdv;
    }
    __syncthreads();
    float v  = row[tid];
    float s1 = v, s2 = v*v;
    for (int off = 32; off >= 1; off >>= 1) {
        s1 += __shfl_down(s1, off, 64);
        s2 += __shfl_down(s2, off, 64);
    }
    if ((tid & 63) == 0) { red[tid >> 6] = s1; red[4 + (tid >> 6)] = s2; }
    __syncthreads();
    float S1 = red[0] + red[1] + red[2] + red[3];
    float S2 = red[4] + red[5] + red[6] + red[7];
    float mu  = S1 / 256.0f;
    float var = S2 / 256.0f - mu*mu;
    float inv = 1.0f / sqrtf(var + 1e-5f);
    nrm[tid] = (v - mu)*inv*gamma[tid] + beta[tid];
    __syncthreads();
    float acc0 = b2[tid], acc1 = b2[tid + 256];
#pragma unroll 4
    for (int j = 0; j < 256; ++j) {
        float nv = nrm[j];
        const float* wr = w2t + (size_t)j*512;
        acc0 += wr[tid]       * nv;
        acc1 += wr[tid + 256] * nv;
    }
    out[(size_t)b*512 + tid]       = acc0;
    out[(size_t)b*512 + tid + 256] = acc1;
}

// ---------------------------------------------------------------------------
extern "C" void kernel_launch(void* const* d_in, const int* in_sizes, int n_in,
                              void* d_out, int out_size, void* d_ws, size_t ws_size,
                              hipStream_t stream) {
    const float* x      = (const float*)d_in[0];
    const float* bp     = (const float*)d_in[1];
    const float* w_lin1 = (const float*)d_in[2];
    const float* b_lin1 = (const float*)d_in[3];
    const float* wc1    = (const float*)d_in[4];
    const float* bc1    = (const float*)d_in[5];
    const float* wc2    = (const float*)d_in[6];
    const float* bc2    = (const float*)d_in[7];
    const float* wc3    = (const float*)d_in[8];
    const float* bc3    = (const float*)d_in[9];
    const float* wa1    = (const float*)d_in[10];
    const float* ba1    = (const float*)d_in[11];
    const float* wa2    = (const float*)d_in[12];
    const float* ba2    = (const float*)d_in[13];
    const float* gamma  = (const float*)d_in[14];
    const float* beta   = (const float*)d_in[15];
    const float* wl2    = (const float*)d_in[16];
    const float* bl2    = (const float*)d_in[17];

    float* ws   = (float*)d_ws;
    float* bs   = ws + OFF_BS;
    ushort_t* weh  = (ushort_t*)(ws + OFF_WEFF);
    ushort_t* wel  = weh + 64*320;
    float* wtail   = ws + OFF_WTAIL;
    ushort_t* w1h  = (ushort_t*)(ws + OFF_W1);
    ushort_t* w1l  = w1h + 3*128*64;
    ushort_t* w2h  = (ushort_t*)(ws + OFF_W2);
    ushort_t* w2l  = w2h + 3*128*128;
    ushort_t* w3h  = (ushort_t*)(ws + OFF_W3);
    ushort_t* w3l  = w3h + 3*128*128;
    ushort_t* wa1h = (ushort_t*)(ws + OFF_WA1);
    ushort_t* wa1l = wa1h + 64*128;
    ushort_t* wa2h = (ushort_t*)(ws + OFF_WA2);
    ushort_t* wa2l = wa2h + 128*64;
    float* pm   = ws + OFF_PM;
    float* ps   = ws + OFF_PS;
    float* pcm  = ws + OFF_PCM;
    float* pcq  = ws + OFF_PCQ;
    ushort_t* Hs = (ushort_t*)(ws + OFF_HS);
    float* wl2t  = ws + OFF_WL2T;

    sort_kernel<<<dim3(1), dim3(64), 0, stream>>>(bp, bs);
    prep_kernel<<<dim3(1136), dim3(256), 0, stream>>>(bs, w_lin1, wc1, wc2, wc3, wa1, wa2,
                                                      wl2, weh, wel, wtail, w1h, w1l,
                                                      w2h, w2l, w3h, w3l, wa1h, wa1l,
                                                      wa2h, wa2l, wl2t);
    // h = relu(x @ Weff^T + b_lin1) -> single bf16 plane
    lin1_mfma<<<dim3(R_/128), dim3(256), 0, stream>>>(x, weh, wtail, b_lin1, Hs);
    // conv1+conv2+conv3+ASP fused, per (80-chunk, b); i1 and i3 never leave LDS
    dconv123_asp<<<dim3(NCH, B_), dim3(512), 0, stream>>>(Hs, w1h, w2h, w3h,
                                                          bc1, bc2, bc3,
                                                          wa1h, wa2h, ba1, ba2,
                                                          pm, ps, pcm, pcq);
    // global combine + stats + LN + coalesced 256->512 linear
    final_kernel<<<dim3(B_), dim3(256), 0, stream>>>(pcm, pcq, pm, ps, gamma, beta,
                                                     wl2t, bl2, (float*)d_out);
}

// Round 26
// 232.137 us; speedup vs baseline: 1.1423x; 1.1423x over previous
//
#include <hip/hip_runtime.h>
#include <math.h>

// ---------------------------------------------------------------------------
// ResCNN_ASP_SpeakerEncoder — FINAL = v23 (measured best: 240.4us).
// v24 (TT=64) and v25 (TT=80) proved occupancy is not the lever (issue-bound);
// both regressed via halo/FETCH/partial-combine inflation. v23 restored.
// Single-pass bf16 MFMA everywhere; conv1+conv2+conv3+ASP fused; i1/i3 never
// leave LDS; fast tanh/exp; swizzled LDS; absmax 0.015625.
// ---------------------------------------------------------------------------

constexpr int B_  = 64;
constexpr int T_  = 3000;
constexpr int NB_ = 257;   // NBINS
constexpr int R_  = B_ * T_;           // 192000 rows
constexpr int NCH = 24;                // chunks (24 x 128)

// workspace layout (float offsets)
constexpr size_t OFF_BS    = 0;
constexpr size_t OFF_WEFF  = 128;                          // ushort hi[64*320]+lo
constexpr size_t OFF_WTAIL = OFF_WEFF + 20480;
constexpr size_t OFF_W1    = OFF_WTAIL + 128;              // ushort hi+lo 3*128*64
constexpr size_t OFF_W2    = OFF_W1  + 3*64*128;
constexpr size_t OFF_W3    = OFF_W2  + 3*128*128;
constexpr size_t OFF_WA1   = OFF_W3  + 3*128*128;
constexpr size_t OFF_WA2   = OFF_WA1 + 8192;
constexpr size_t SZ_P      = (size_t)B_*NCH*128;
constexpr size_t OFF_PM    = OFF_WA2 + 8192;
constexpr size_t OFF_PS    = OFF_PM  + SZ_P;
constexpr size_t OFF_PCM   = OFF_PS  + SZ_P;
constexpr size_t OFF_PCQ   = OFF_PCM + SZ_P;
// single bf16 planes
constexpr size_t OFF_HS    = OFF_PCQ + SZ_P;               // h  [R*64]u
constexpr size_t OFF_AS    = OFF_HS  + (size_t)R_*32;      // slack (DMA overrun)
constexpr size_t OFF_WL2T  = OFF_AS  + (size_t)R_*64 + 4096; // fp32 [256][512]

typedef __attribute__((ext_vector_type(8))) short  bf16x8;
typedef __attribute__((ext_vector_type(4))) float  f32x4;
typedef __attribute__((ext_vector_type(4), aligned(4))) float float4a;
typedef unsigned short ushort_t;

typedef __attribute__((address_space(3))) unsigned int        as3_u32;
typedef const __attribute__((address_space(1))) unsigned int  as1_u32c;
__device__ __forceinline__ void gload16(const void* g, void* l) {
    __builtin_amdgcn_global_load_lds((as1_u32c*)g, (as3_u32*)l, 16, 0, 0);
}

__device__ inline ushort_t f2bf(float f) {                // RNE f32->bf16
    unsigned u = __float_as_uint(f);
    unsigned r = u + 0x7FFFu + ((u >> 16) & 1u);
    return (ushort_t)(r >> 16);
}
__device__ inline float bf2f(ushort_t h) {
    return __uint_as_float(((unsigned)h) << 16);
}
__device__ inline void split2(float v, ushort_t &h, ushort_t &l) {
    h = f2bf(v);
    l = f2bf(v - bf2f(h));
}

// fast tanh: (e^{2x}-1)/(e^{2x}+1), clamp +-15
__device__ inline float fast_tanh(float x) {
    float cx = fminf(fmaxf(x, -15.0f), 15.0f);
    float e  = __expf(2.0f * cx);
    return __fdividef(e - 1.0f, e + 1.0f);
}

// pack 4 f32 -> 4 bf16 (RNE, 2 u32)
__device__ inline void pack_hi4(float x, float y, float z, float w, uint2 &ph) {
    unsigned hx, hy;
    asm("v_cvt_pk_bf16_f32 %0, %1, %2" : "=v"(hx) : "v"(x), "v"(y));
    asm("v_cvt_pk_bf16_f32 %0, %1, %2" : "=v"(hy) : "v"(z), "v"(w));
    ph.x = hx; ph.y = hy;
}

// ---------------------------------------------------------------------------
__global__ void sort_kernel(const float* __restrict__ bp, float* __restrict__ bs) {
    if (threadIdx.x == 0) {
        float tmp[82];
        for (int i = 0; i < 82; ++i) tmp[i] = bp[i];
        for (int i = 1; i < 82; ++i) {
            float key = tmp[i];
            int j = i - 1;
            while (j >= 0 && tmp[j] > key) { tmp[j+1] = tmp[j]; --j; }
            tmp[j+1] = key;
        }
        for (int i = 0; i < 82; ++i) bs[i] = tmp[i];
    }
}

// Fragment-order packing (B: lane&15=col, lane>>4=k-octet; A: lane&15=row),
// plus fp32 wl2 transpose [256 j][512 o]. (lo planes still written; unused.)
__global__ void prep_kernel(const float* __restrict__ bs, const float* __restrict__ wl1,
                            const float* __restrict__ wc1, const float* __restrict__ wc2,
                            const float* __restrict__ wc3, const float* __restrict__ wa1,
                            const float* __restrict__ wa2, const float* __restrict__ wl2,
                            ushort_t* __restrict__ weh, ushort_t* __restrict__ wel,
                            float* __restrict__ wtail,
                            ushort_t* __restrict__ w1h, ushort_t* __restrict__ w1l,
                            ushort_t* __restrict__ w2h, ushort_t* __restrict__ w2l,
                            ushort_t* __restrict__ w3h, ushort_t* __restrict__ w3l,
                            ushort_t* __restrict__ wa1h, ushort_t* __restrict__ wa1l,
                            ushort_t* __restrict__ wa2h, ushort_t* __restrict__ wa2l,
                            float* __restrict__ wl2t) {
    int gid = blockIdx.x * 256 + threadIdx.x;
    if (gid < 64*320) {                            // Weff[o][f]
        int o = gid / 320, f = gid % 320;
        if (f > 256) return;
        float acc = 0.0f;
        if (f == 0) acc = wl1[o*80];               // filt[:,:,0] = x[:,:,0]
        else {
            for (int n = 1; n < 79; ++n) {
                float bn = bs[n], bn1 = bs[n+1], bn2 = bs[n+2];
                int ibn  = (int)floorf(bn);
                int ibn1 = (int)floorf(bn1);
                int ibn2 = (int)floorf(bn2);
                float fbv = 0.0f;
                if (f >= ibn && f < ibn1) {
                    float d = (bn1-bn)*(bn1-bn);
                    fbv = ((float)f - bn) / (d > 0.0f ? d : 1.0f);
                } else if (f >= ibn1 && f < ibn2) {
                    float d = (bn2-bn1)*(bn2-bn1);
                    fbv = (bn2 - (float)f) / (d > 0.0f ? d : 1.0f);
                }
                acc += wl1[o*80 + n] * fbv;
            }
        }
        if (f == 256) { wtail[o] = acc; return; }
        int kc = f >> 5, lane = ((f & 31) >> 3)*16 + (o & 15), e = f & 7;
        size_t dst = (((size_t)kc*4 + (o >> 4))*64 + lane)*8 + e;
        split2(acc, weh[dst], wel[dst]);
        return;
    }
    gid -= 64*320;
    if (gid < 3*128*64) {                          // conv1: [k][c][ci=64]
        int k = gid / (128*64), rem = gid % (128*64);
        int c = rem >> 6, ci = rem & 63;
        float v = wc1[(c*64 + ci)*3 + k];
        int lane = ((ci & 31) >> 3)*16 + (c & 15), e = ci & 7;
        size_t dst = ((((size_t)k*2 + (ci >> 5))*8 + (c >> 4))*64 + lane)*8 + e;
        split2(v, w1h[dst], w1l[dst]);
        return;
    }
    gid -= 3*128*64;
    if (gid < 3*128*128) {                         // conv2
        int k = gid / (128*128), rem = gid % (128*128);
        int c = rem >> 7, ci = rem & 127;
        float v = wc2[(c*128 + ci)*3 + k];
        int lane = ((ci & 31) >> 3)*16 + (c & 15), e = ci & 7;
        size_t dst = ((((size_t)k*4 + (ci >> 5))*8 + (c >> 4))*64 + lane)*8 + e;
        split2(v, w2h[dst], w2l[dst]);
        return;
    }
    gid -= 3*128*128;
    if (gid < 3*128*128) {                         // conv3
        int k = gid / (128*128), rem = gid % (128*128);
        int c = rem >> 7, ci = rem & 127;
        float v = wc3[(c*128 + ci)*3 + k];
        int lane = ((ci & 31) >> 3)*16 + (c & 15), e = ci & 7;
        size_t dst = ((((size_t)k*4 + (ci >> 5))*8 + (c >> 4))*64 + lane)*8 + e;
        split2(v, w3h[dst], w3l[dst]);
        return;
    }
    gid -= 3*128*128;
    if (gid < 64*128) {                            // wa1 [c=64][ci=128]
        int c = gid >> 7, ci = gid & 127;
        float v = wa1[gid];
        int lane = ((ci & 31) >> 3)*16 + (c & 15), e = ci & 7;
        size_t dst = (((size_t)(ci >> 5)*4 + (c >> 4))*64 + lane)*8 + e;
        split2(v, wa1h[dst], wa1l[dst]);
        return;
    }
    gid -= 64*128;
    if (gid < 128*64) {                            // wa2 [n=128][ci=64] (A op)
        int n = gid >> 6, ci = gid & 63;
        float v = wa2[gid];
        int lane = ((ci & 31) >> 3)*16 + (n & 15), e = ci & 7;
        size_t dst = (((size_t)(ci >> 5)*8 + (n >> 4))*64 + lane)*8 + e;
        split2(v, wa2h[dst], wa2l[dst]);
        return;
    }
    gid -= 128*64;
    if (gid < 256*512) {                           // wl2T[j][o] <- wl2[o][j]
        int j = gid >> 9, o = gid & 511;
        wl2t[gid] = wl2[(size_t)o*256 + j];
        return;
    }
}

// ---------------------------------------------------------------------------
// lin1: h = relu(x @ Weff^T + b); x staged as single bf16; 1-pass MFMA.
__launch_bounds__(256)
__global__ void lin1_mfma(const float* __restrict__ X,
                          const ushort_t* __restrict__ Wh,
                          const float* __restrict__ wtail,
                          const float* __restrict__ bias,
                          ushort_t* __restrict__ Hs) {
    __shared__ __align__(16) ushort_t ash[128*64];
    __shared__ float xs[128];
    __shared__ float wts[64];
    const int tid  = threadIdx.x;
    const int lane = tid & 63;
    const int wid  = tid >> 6;
    const int wy   = wid >> 1, wx = wid & 1;
    const int l16  = lane & 15, l4 = lane >> 4;
    const int r0   = blockIdx.x * 128;

    if (tid < 128)       xs[tid] = X[(size_t)(r0 + tid)*NB_ + 256];
    else if (tid < 192)  wts[tid - 128] = wtail[tid - 128];

#define LIN1_LOAD(dst, k0)                                            \
    _Pragma("unroll")                                                 \
    for (int i = 0; i < 8; ++i) {                                     \
        int q = tid + i*256; int r = q >> 4, cc = (q & 15) << 2;      \
        dst[i] = *(const float4a*)(X + (size_t)(r0 + r)*NB_ + (k0) + cc); \
    }
#define LIN1_CW(src)                                                  \
    _Pragma("unroll")                                                 \
    for (int i = 0; i < 8; ++i) {                                     \
        int q = tid + i*256; int r = q >> 4, cc = (q & 15) << 2;      \
        uint2 ph;                                                     \
        pack_hi4(src[i].x, src[i].y, src[i].z, src[i].w, ph);         \
        unsigned byte = ((unsigned)(r*64 + cc))*2u ^ ((unsigned)((r & 7) << 4)); \
        *(uint2*)((char*)ash + byte) = ph;                            \
    }

    float4a bufA[8], bufB[8];
    LIN1_LOAD(bufA, 0);

    f32x4 acc[4][2];
    const f32x4 z = {0.f,0.f,0.f,0.f};
#pragma unroll
    for (int m = 0; m < 4; ++m) { acc[m][0] = z; acc[m][1] = z; }

#pragma unroll
    for (int ck = 0; ck < 4; ++ck) {
        const float4a* cur = (ck & 1) ? bufB : bufA;
        float4a*       nxt = (ck & 1) ? bufA : bufB;
        if (ck < 3) LIN1_LOAD(nxt, (ck + 1)*64);
        LIN1_CW(cur);
        __syncthreads();
#pragma unroll
        for (int kk = 0; kk < 64; kk += 32) {
            bf16x8 bh[2];
#pragma unroll
            for (int n = 0; n < 2; ++n) {
                size_t off = (((size_t)(ck*2 + (kk >> 5))*4 + wx*2 + n)*64 + lane)*8;
                bh[n] = *(const bf16x8*)(Wh + off);
            }
            bf16x8 fh[4];
#pragma unroll
            for (int m = 0; m < 4; ++m) {
                int r = wy*64 + m*16 + l16;
                unsigned byte = ((unsigned)(r*64 + kk + l4*8))*2u ^ ((unsigned)((r & 7) << 4));
                fh[m] = *(const bf16x8*)((const char*)ash + byte);
            }
#pragma unroll
            for (int m = 0; m < 4; ++m)
#pragma unroll
                for (int n = 0; n < 2; ++n)
                    acc[m][n] = __builtin_amdgcn_mfma_f32_16x16x32_bf16(fh[m], bh[n], acc[m][n], 0, 0, 0);
        }
        __syncthreads();
    }
#undef LIN1_LOAD
#undef LIN1_CW

#pragma unroll
    for (int m = 0; m < 4; ++m)
#pragma unroll
        for (int n = 0; n < 2; ++n) {
            int c = wx*32 + n*16 + l16;
            float bv = bias[c];
            float wc = wts[c];
            int rbl = wy*64 + m*16 + l4*4;
#pragma unroll
            for (int rg = 0; rg < 4; ++rg) {
                int rl = rbl + rg;
                float v = fmaxf(acc[m][n][rg] + bv + xs[rl]*wc, 0.0f);
                Hs[(size_t)(r0 + rl)*64 + c] = f2bf(v);
            }
        }
}

// ---------------------------------------------------------------------------
// Fused conv1+conv2+conv3+ASP, TT=128 per (chunk, b). 1-pass MFMA.
__launch_bounds__(512)
__global__ void dconv123_asp(const ushort_t* __restrict__ Hs,
                             const ushort_t* __restrict__ W1h,
                             const ushort_t* __restrict__ W2h,
                             const ushort_t* __restrict__ W3h,
                             const float* __restrict__ bc1, const float* __restrict__ bc2,
                             const float* __restrict__ bc3,
                             const ushort_t* __restrict__ Wa1h,
                             const ushort_t* __restrict__ Wa2h,
                             const float* __restrict__ ba1, const float* __restrict__ ba2,
                             float* __restrict__ pm, float* __restrict__ ps,
                             float* __restrict__ pcm, float* __restrict__ pcq) {
    __shared__ __align__(16) char smem[73728];
    ushort_t* hs_ = (ushort_t*)smem;               // [148][64] rows t0-10..t0+137
    ushort_t* ss_ = (ushort_t*)smem;               // s/i3 [144][128] (hs dead first)
    ushort_t* i1s = (ushort_t*)(smem + 36864);     // i1 [144][128]
    ushort_t* vs_ = (ushort_t*)(smem + 36864);     // v [128][64] (i1 dead)

    const int tid  = threadIdx.x;
    const int lane = tid & 63;
    const int wid  = tid >> 6;            // 0..7
    const int l16  = lane & 15, l4 = lane >> 4;
    const int ch   = blockIdx.x;
    const int b    = blockIdx.y;
    const int t0   = ch * 128;

    // ---- stage h rows [t0-10, t0+138): 148 rows x 64ch, (r&7) pre-swizzle ----
    const long long rowbase_h = ((long long)b*T_ + (t0 - 10)) * 64;
    for (int c0 = wid*64; c0 < 1280; c0 += 512) {  // 1184 real chunks, pad 1280
        int ck = c0 + lane;
        int r  = ck >> 3;
        int sc = ck ^ (r & 7);
        gload16(Hs + rowbase_h + (long long)sc*8, (char*)hs_ + (size_t)c0*16);
    }
    __syncthreads();
    if (t0 < 10 || t0 + 138 > T_) {                // zero OOB-global h rows
        for (int idx = tid; idx < 148*64/4; idx += 512) {
            int e = idx << 2;
            int r = e >> 6, ci = e & 63;
            int t = t0 - 10 + r;
            if (t < 0 || t >= T_) {
                unsigned byte = ((unsigned)(r*64 + ci))*2u ^ ((unsigned)((r & 7) << 4));
                *(uint2*)((char*)hs_ + byte) = make_uint2(0u, 0u);
            }
        }
        __syncthreads();
    }

    // ---- phase 0: conv1 over 144 i1 rows (reads hs) -> i1s (OOB t -> 0) ----
    {
        f32x4 acc[9];
        const f32x4 z = {0.f,0.f,0.f,0.f};
#pragma unroll
        for (int m = 0; m < 9; ++m) acc[m] = z;
#pragma unroll
        for (int k = 0; k < 3; ++k) {
#pragma unroll
            for (int cb = 0; cb < 2; ++cb) {
                size_t off = ((((size_t)k*2 + cb)*8 + wid)*64 + lane)*8;
                bf16x8 bh = *(const bf16x8*)(W1h + off);
#pragma unroll
                for (int m = 0; m < 9; ++m) {
                    int r = m*16 + l16 + 2*k;          // hs row, in [0,147]
                    unsigned byte = ((unsigned)(r*64 + cb*32 + l4*8))*2u
                                  ^ ((unsigned)((r & 7) << 4));
                    bf16x8 ah = *(const bf16x8*)((const char*)hs_ + byte);
                    acc[m] = __builtin_amdgcn_mfma_f32_16x16x32_bf16(ah, bh, acc[m], 0, 0, 0);
                }
            }
        }
        const int c = wid*16 + l16;
        const float bv = bc1[c];
#pragma unroll
        for (int m = 0; m < 9; ++m) {
#pragma unroll
            for (int rg = 0; rg < 4; ++rg) {
                int rl = m*16 + l4*4 + rg;             // i1 local row 0..143
                int t  = t0 - 8 + rl;
                float v = (t >= 0 && t < T_) ? (acc[m][rg] + bv) : 0.0f;
                unsigned byte = ((unsigned)(rl*128 + c))*2u ^ ((unsigned)((rl & 15) << 4));
                *(ushort_t*)((char*)i1s + byte) = f2bf(v);
            }
        }
    }
    __syncthreads();                       // hs reads done; i1s ready

    // ---- phase 1: conv2 over all 144 local rows -> s = conv2 + bc2 + 2*i1 ----
    {
        f32x4 acc[9];
        const f32x4 z = {0.f,0.f,0.f,0.f};
#pragma unroll
        for (int m = 0; m < 9; ++m) acc[m] = z;
#pragma unroll
        for (int k = 0; k < 3; ++k) {
#pragma unroll
            for (int cb = 0; cb < 4; ++cb) {
                size_t off = ((((size_t)k*4 + cb)*8 + wid)*64 + lane)*8;
                bf16x8 bh = *(const bf16x8*)(W2h + off);
#pragma unroll
                for (int m = 0; m < 9; ++m) {
                    int r = m*16 + l16 + k*3 - 3;
                    r = min(max(r, 0), 143);  // garbage edge rows; never consumed
                    unsigned byte = ((unsigned)(r*128 + cb*32 + l4*8))*2u
                                  ^ ((unsigned)((r & 15) << 4));
                    bf16x8 ah = *(const bf16x8*)((const char*)i1s + byte);
                    acc[m] = __builtin_amdgcn_mfma_f32_16x16x32_bf16(ah, bh, acc[m], 0, 0, 0);
                }
            }
        }
        const int c = wid*16 + l16;
        const float bv = bc2[c];
#pragma unroll
        for (int m = 0; m < 9; ++m) {
#pragma unroll
            for (int rg = 0; rg < 4; ++rg) {
                int rl = m*16 + l4*4 + rg;
                int t  = t0 - 8 + rl;
                float v = 0.0f;
                unsigned byte = ((unsigned)(rl*128 + c))*2u ^ ((unsigned)((rl & 15) << 4));
                if (t >= 0 && t < T_) {
                    float cen = bf2f(*(const ushort_t*)((const char*)i1s + byte));
                    v = acc[m][rg] + bv + 2.0f*cen;
                }
                *(ushort_t*)((char*)ss_ + byte) = f2bf(v);
            }
        }
    }
    __syncthreads();

    // ---- phase 2: conv3 + residual into REGISTERS (reads s) ----
    float i3r[8][4];
    {
        f32x4 acc[8];
        const f32x4 z = {0.f,0.f,0.f,0.f};
#pragma unroll
        for (int m = 0; m < 8; ++m) acc[m] = z;
#pragma unroll
        for (int k = 0; k < 3; ++k) {
#pragma unroll
            for (int cb = 0; cb < 4; ++cb) {
                size_t off = ((((size_t)k*4 + cb)*8 + wid)*64 + lane)*8;
                bf16x8 bh = *(const bf16x8*)(W3h + off);
#pragma unroll
                for (int m = 0; m < 8; ++m) {
                    int r = 8 + m*16 + l16 + k*4 - 4;  // in [4,139]
                    unsigned byte = ((unsigned)(r*128 + cb*32 + l4*8))*2u
                                  ^ ((unsigned)((r & 15) << 4));
                    bf16x8 ah = *(const bf16x8*)((const char*)ss_ + byte);
                    acc[m] = __builtin_amdgcn_mfma_f32_16x16x32_bf16(ah, bh, acc[m], 0, 0, 0);
                }
            }
        }
        const int c = wid*16 + l16;
        const float bv = bc3[c];
#pragma unroll
        for (int m = 0; m < 8; ++m)
#pragma unroll
            for (int rg = 0; rg < 4; ++rg) {
                int rl = 8 + m*16 + l4*4 + rg;         // in [8,136)
                unsigned byte = ((unsigned)(rl*128 + c))*2u ^ ((unsigned)((rl & 15) << 4));
                float cen = bf2f(*(const ushort_t*)((const char*)ss_ + byte));
                i3r[m][rg] = acc[m][rg] + bv + cen;
            }
    }
    __syncthreads();                       // all s reads complete
    // write i3 over s (rows [8,136) = t [t0, t0+128))
    {
        const int c = wid*16 + l16;
#pragma unroll
        for (int m = 0; m < 8; ++m)
#pragma unroll
            for (int rg = 0; rg < 4; ++rg) {
                int rl = 8 + m*16 + l4*4 + rg;
                unsigned byte = ((unsigned)(rl*128 + c))*2u ^ ((unsigned)((rl & 15) << 4));
                *(ushort_t*)((char*)ss_ + byte) = f2bf(i3r[m][rg]);
            }
    }
    __syncthreads();                       // i3 tile ready (i1 dead)

    // ---- ASP stage 1: v = tanh(i3 @ wa1^T + ba1)  (wave: rowhalf x coltile) ----
    {
        const int wy = wid >> 2;          // 0..1: rows wy*64 + m*16
        const int wx = wid & 3;           // 0..3: cols wx*16
        f32x4 acc1[4];
        const f32x4 z = {0.f,0.f,0.f,0.f};
#pragma unroll
        for (int m = 0; m < 4; ++m) acc1[m] = z;
#pragma unroll
        for (int kc = 0; kc < 4; ++kc) {
            size_t off = (((size_t)kc*4 + wx)*64 + lane)*8;
            bf16x8 bh = *(const bf16x8*)(Wa1h + off);
#pragma unroll
            for (int m = 0; m < 4; ++m) {
                int rl = 8 + wy*64 + m*16 + l16;       // i3 row
                unsigned byte = ((unsigned)(rl*128 + kc*32 + l4*8))*2u
                              ^ ((unsigned)((rl & 15) << 4));
                bf16x8 ah = *(const bf16x8*)((const char*)ss_ + byte);
                acc1[m] = __builtin_amdgcn_mfma_f32_16x16x32_bf16(ah, bh, acc1[m], 0, 0, 0);
            }
        }
        const int c = wx*16 + l16;
        const float bv = ba1[c];
#pragma unroll
        for (int m = 0; m < 4; ++m)
#pragma unroll
            for (int rg = 0; rg < 4; ++rg) {
                float v = fast_tanh(acc1[m][rg] + bv);
                int r = wy*64 + m*16 + l4*4 + rg;      // t row in [0,128)
                unsigned byte = ((unsigned)(r*64 + c))*2u ^ ((unsigned)((r & 7) << 4));
                *(ushort_t*)((char*)vs_ + byte) = f2bf(v);
            }
    }
    __syncthreads();

    // ---- ASP stage 2 + softmax partials + weighted stats ----
    {
        f32x4 acc2[8];
        const f32x4 z = {0.f,0.f,0.f,0.f};
#pragma unroll
        for (int j = 0; j < 8; ++j) acc2[j] = z;
#pragma unroll
        for (int kc = 0; kc < 2; ++kc) {
            size_t off = (((size_t)kc*8 + wid)*64 + lane)*8;
            bf16x8 awh = *(const bf16x8*)(Wa2h + off);
#pragma unroll
            for (int j = 0; j < 8; ++j) {
                int t = j*16 + l16;
                unsigned byte = ((unsigned)(t*64 + kc*32 + l4*8))*2u
                              ^ ((unsigned)((t & 7) << 4));
                bf16x8 bv_ = *(const bf16x8*)((const char*)vs_ + byte);
                acc2[j] = __builtin_amdgcn_mfma_f32_16x16x32_bf16(awh, bv_, acc2[j], 0, 0, 0);
            }
        }
        const float4 bvv = *(const float4*)&ba2[wid*16 + l4*4];
        const float bva[4] = {bvv.x, bvv.y, bvv.z, bvv.w};
#pragma unroll
        for (int rg = 0; rg < 4; ++rg) {
            const int n = wid*16 + l4*4 + rg;
            float mx = -INFINITY;
#pragma unroll
            for (int j = 0; j < 8; ++j) {
                int tg = t0 + j*16 + l16;
                if (tg < T_) mx = fmaxf(mx, acc2[j][rg] + bva[rg]);
            }
            mx = fmaxf(mx, __shfl_xor(mx, 1));
            mx = fmaxf(mx, __shfl_xor(mx, 2));
            mx = fmaxf(mx, __shfl_xor(mx, 4));
            mx = fmaxf(mx, __shfl_xor(mx, 8));
            float se = 0.0f, am = 0.0f, aq = 0.0f;
#pragma unroll
            for (int j = 0; j < 8; ++j) {
                int tl = j*16 + l16;
                int tg = t0 + tl;
                if (tg < T_) {
                    float p = __expf(acc2[j][rg] + bva[rg] - mx);
                    int rl = tl + 8;
                    unsigned byte = ((unsigned)(rl*128 + n))*2u ^ ((unsigned)((rl & 15) << 4));
                    float x = bf2f(*(const ushort_t*)((const char*)ss_ + byte));
                    se += p; am += p*x; aq += p*x*x;
                }
            }
#pragma unroll
            for (int d = 1; d <= 8; d <<= 1) {
                se += __shfl_xor(se, d);
                am += __shfl_xor(am, d);
                aq += __shfl_xor(aq, d);
            }
            if (l16 == 0) {
                size_t o = ((size_t)b*NCH + ch)*128 + n;
                pm[o]  = mx;
                ps[o]  = se;
                pcm[o] = am;
                pcq[o] = aq;
            }
        }
    }
}

// ---------------------------------------------------------------------------
// final: global softmax combine + stats + layernorm(256) + coalesced linear.
__launch_bounds__(256)
__global__ void final_kernel(const float* __restrict__ pcm, const float* __restrict__ pcq,
                             const float* __restrict__ pm, const float* __restrict__ ps,
                             const float* __restrict__ gamma, const float* __restrict__ beta,
                             const float* __restrict__ w2t, const float* __restrict__ b2,
                             float* __restrict__ out) {
    __shared__ float row[256];
    __shared__ float nrm[256];
    __shared__ float red[8];
    const int tid = threadIdx.x, b = blockIdx.x;
    if (tid < 128) {
        float M = -INFINITY;
        for (int ch = 0; ch < NCH; ++ch)
            M = fmaxf(M, pm[((size_t)b*NCH + ch)*128 + tid]);
        float S = 0.0f, sm = 0.0f, sq = 0.0f;
        for (int ch = 0; ch < NCH; ++ch) {
            size_t o = ((size_t)b*NCH + ch)*128 + tid;
            float m = pm[o];
            if (m > -INFINITY) {
                float e = expf(m - M);
                S  += ps[o]*e;
                sm += pcm[o]*e;
                sq += pcq[o]*e;
            }
        }
        float mean = sm / S;
        float q    = sq / S;
        float resid = q - mean*mean;
        float stdv  = sqrtf(fmaxf(resid, 1e-9f));
        row[tid]       = mean;
        row[128 + tid] = stdv;
    }
    __syncthreads();
    float v  = row[tid];
    float s1 = v, s2 = v*v;
    for (int off = 32; off >= 1; off >>= 1) {
        s1 += __shfl_down(s1, off, 64);
        s2 += __shfl_down(s2, off, 64);
    }
    if ((tid & 63) == 0) { red[tid >> 6] = s1; red[4 + (tid >> 6)] = s2; }
    __syncthreads();
    float S1 = red[0] + red[1] + red[2] + red[3];
    float S2 = red[4] + red[5] + red[6] + red[7];
    float mu  = S1 / 256.0f;
    float var = S2 / 256.0f - mu*mu;
    float inv = 1.0f / sqrtf(var + 1e-5f);
    nrm[tid] = (v - mu)*inv*gamma[tid] + beta[tid];
    __syncthreads();
    float acc0 = b2[tid], acc1 = b2[tid + 256];
#pragma unroll 4
    for (int j = 0; j < 256; ++j) {
        float nv = nrm[j];
        const float* wr = w2t + (size_t)j*512;
        acc0 += wr[tid]       * nv;
        acc1 += wr[tid + 256] * nv;
    }
    out[(size_t)b*512 + tid]       = acc0;
    out[(size_t)b*512 + tid + 256] = acc1;
}

// ---------------------------------------------------------------------------
extern "C" void kernel_launch(void* const* d_in, const int* in_sizes, int n_in,
                              void* d_out, int out_size, void* d_ws, size_t ws_size,
                              hipStream_t stream) {
    const float* x      = (const float*)d_in[0];
    const float* bp     = (const float*)d_in[1];
    const float* w_lin1 = (const float*)d_in[2];
    const float* b_lin1 = (const float*)d_in[3];
    const float* wc1    = (const float*)d_in[4];
    const float* bc1    = (const float*)d_in[5];
    const float* wc2    = (const float*)d_in[6];
    const float* bc2    = (const float*)d_in[7];
    const float* wc3    = (const float*)d_in[8];
    const float* bc3    = (const float*)d_in[9];
    const float* wa1    = (const float*)d_in[10];
    const float* ba1    = (const float*)d_in[11];
    const float* wa2    = (const float*)d_in[12];
    const float* ba2    = (const float*)d_in[13];
    const float* gamma  = (const float*)d_in[14];
    const float* beta   = (const float*)d_in[15];
    const float* wl2    = (const float*)d_in[16];
    const float* bl2    = (const float*)d_in[17];

    float* ws   = (float*)d_ws;
    float* bs   = ws + OFF_BS;
    ushort_t* weh  = (ushort_t*)(ws + OFF_WEFF);
    ushort_t* wel  = weh + 64*320;
    float* wtail   = ws + OFF_WTAIL;
    ushort_t* w1h  = (ushort_t*)(ws + OFF_W1);
    ushort_t* w1l  = w1h + 3*128*64;
    ushort_t* w2h  = (ushort_t*)(ws + OFF_W2);
    ushort_t* w2l  = w2h + 3*128*128;
    ushort_t* w3h  = (ushort_t*)(ws + OFF_W3);
    ushort_t* w3l  = w3h + 3*128*128;
    ushort_t* wa1h = (ushort_t*)(ws + OFF_WA1);
    ushort_t* wa1l = wa1h + 64*128;
    ushort_t* wa2h = (ushort_t*)(ws + OFF_WA2);
    ushort_t* wa2l = wa2h + 128*64;
    float* pm   = ws + OFF_PM;
    float* ps   = ws + OFF_PS;
    float* pcm  = ws + OFF_PCM;
    float* pcq  = ws + OFF_PCQ;
    ushort_t* Hs = (ushort_t*)(ws + OFF_HS);
    float* wl2t  = ws + OFF_WL2T;

    sort_kernel<<<dim3(1), dim3(64), 0, stream>>>(bp, bs);
    prep_kernel<<<dim3(1136), dim3(256), 0, stream>>>(bs, w_lin1, wc1, wc2, wc3, wa1, wa2,
                                                      wl2, weh, wel, wtail, w1h, w1l,
                                                      w2h, w2l, w3h, w3l, wa1h, wa1l,
                                                      wa2h, wa2l, wl2t);
    // h = relu(x @ Weff^T + b_lin1) -> single bf16 plane
    lin1_mfma<<<dim3(R_/128), dim3(256), 0, stream>>>(x, weh, wtail, b_lin1, Hs);
    // conv1+conv2+conv3+ASP fused, per (128-chunk, b); i1 and i3 never leave LDS
    dconv123_asp<<<dim3(NCH, B_), dim3(512), 0, stream>>>(Hs, w1h, w2h, w3h,
                                                          bc1, bc2, bc3,
                                                          wa1h, wa2h, ba1, ba2,
                                                          pm, ps, pcm, pcq);
    // global combine + stats + LN + coalesced 256->512 linear
    final_kernel<<<dim3(B_), dim3(256), 0, stream>>>(pcm, pcq, pm, ps, gamma, beta,
                                                     wl2t, bl2, (float*)d_out);
}